// Round 1
// 458.305 us; speedup vs baseline: 1.0215x; 1.0215x over previous
//
#include <hip/hip_runtime.h>

#define NB    512
#define CIN   12
#define TIN   5000
#define C1    32
#define T1    496
#define T2    95
#define LATD  32
#define HIDD  64

// workspace layout (float offsets)
#define OFS_STATS 0        // 256 floats
#define OFS_W1P   256      // 12*50*32 = 19200, layout [ic][k][oc]
#define OFS_W2P   19456    // 32*25*32 = 25600, layout [ic][k][oc]
#define OFS_Y1    45056    // 512*32*496 = 8126464
#define OFS_Y2    8171520  // 512*32*95  = 1556480
#define OFS_XS    OFS_Y1   // xs[95][512][32] aliases y1 (y1 dead after conv2)

// ---------------- prep: zero stats + repack weights ----------------
__global__ void prep_kernel(const float* __restrict__ w1, const float* __restrict__ w2,
                            float* __restrict__ ws) {
    int idx = blockIdx.x * 256 + threadIdx.x;
    if (idx < 256) ws[idx] = 0.f;
    int j = idx - 256;
    if (j >= 0 && j < 19200) {            // w1p[ic][k][oc], oc fastest
        int ic = j / 1600, r = j % 1600, k = r / 32, oc = r % 32;
        ws[OFS_W1P + j] = w1[oc * 600 + ic * 50 + k];
    }
    int j2 = idx - 19456;
    if (j2 >= 0 && j2 < 25600) {          // w2p[ic][k][oc]
        int ic = j2 / 800, r = j2 % 800, k = r / 32, oc = r % 32;
        ws[OFS_W2P + j2] = w2[oc * 800 + ic * 25 + k];
    }
}

// ---------------- conv1 + bias, fused BN1 stats ----------------
// grid 1024: b = bx>>1, t-tile (256) = bx&1. block 256: ocg=tid&3 (8 oc), tg=tid>>2 (4 t)
// 256-thread blocks: 4 blocks/CU x 4 waves = 16 waves/CU (was 8) -> 4 waves/SIMD to
// hide the per-kp ds_read->FMA latency that left VALUBusy at 51%.
// LDS layout identical to the proven 128-thread version: x skewed +2 per 80 floats,
// weights [k][oc]; double-buffered staging with register prefetch.
__global__ __launch_bounds__(256, 2) void conv1_kernel(const float* __restrict__ x,
                                                       const float* __restrict__ b1,
                                                       float* __restrict__ ws) {
    const float* w1p = ws + OFS_W1P;
    float* y1 = ws + OFS_Y1;
    float* stats = ws + OFS_STATS;
    int b  = blockIdx.x >> 1;
    int t0 = (blockIdx.x & 1) * 256;
    int tid = threadIdx.x;
    int ocg = tid & 3, tg = tid >> 2;         // tg 0..63, 4 t each
    int oc0 = ocg * 8, lt0 = tg * 4;
    // padded base for this tg's 40-float window: pad = +2 per 80 floats
    int xbase  = 41 * tg - (tg & 1);
    int thresh = (tg & 1) ? 40 : 127;         // r >= thresh -> crosses next pad (+2)

    __shared__ __align__(16) float xs_s[2][2664];   // 2600 + skew, double-buffered
    __shared__ __align__(16) float ws_s[2][1600];   // [k][oc] 50*32
    __shared__ float sred[256];

    float acc[8][4];
#pragma unroll
    for (int a = 0; a < 8; ++a)
#pragma unroll
        for (int c = 0; c < 4; ++c) acc[a][c] = 0.f;

    const float* xb = x + (size_t)b * (CIN * TIN) + t0 * 10;
    int nvalid = TIN - t0 * 10;               // 5000 or 2440

    float4 px[3];
    float4 pw[2];

    auto fetch = [&](int ic) {
#pragma unroll
        for (int j = 0; j < 3; ++j) {
            int i = tid + j * 256;
            if (i < 650) {
                int src = 4 * i;
                const float* gp = xb + ic * TIN + src;
                float4 v;
                if (src + 4 <= nvalid) {
                    v = *(const float4*)gp;
                } else {
                    v.x = (src + 0 < nvalid) ? gp[0] : 0.f;
                    v.y = (src + 1 < nvalid) ? gp[1] : 0.f;
                    v.z = (src + 2 < nvalid) ? gp[2] : 0.f;
                    v.w = (src + 3 < nvalid) ? gp[3] : 0.f;
                }
                px[j] = v;
            }
        }
#pragma unroll
        for (int j = 0; j < 2; ++j) {
            int i = tid + j * 256;
            if (i < 400) pw[j] = *(const float4*)(w1p + ic * 1600 + 4 * i);
        }
    };

    fetch(0);
    for (int ic = 0; ic < CIN; ++ic) {
        int cur = ic & 1;
        __syncthreads();                      // buf[cur] free (read 2 iters ago)
#pragma unroll
        for (int j = 0; j < 3; ++j) {
            int i = tid + j * 256;
            if (i < 650) {
                int src = 4 * i;
                int dst = src + (i / 20) * 2; // skew +2 per 80 words
                float2 lo; lo.x = px[j].x; lo.y = px[j].y;
                float2 hi; hi.x = px[j].z; hi.y = px[j].w;
                *(float2*)&xs_s[cur][dst]     = lo;
                *(float2*)&xs_s[cur][dst + 2] = hi;
            }
        }
#pragma unroll
        for (int j = 0; j < 2; ++j) {
            int i = tid + j * 256;
            if (i < 400) *(float4*)&ws_s[cur][4 * i] = pw[j];
        }
        if (ic + 1 < CIN) fetch(ic + 1);      // global loads fly during compute
        __syncthreads();

#pragma unroll 1
        for (int kp = 0; kp < 25; ++kp) {
            const int k = kp * 2;
            const float* wr = &ws_s[cur][k * 32 + oc0];
            float4 w00 = *(const float4*)wr;         // tap k,   oc0..oc0+3
            float4 w01 = *(const float4*)(wr + 4);   // tap k,   oc0+4..7
            float4 w10 = *(const float4*)(wr + 32);  // tap k+1, oc0..oc0+3
            float4 w11 = *(const float4*)(wr + 36);
            float2 xv[4];
#pragma unroll
            for (int jt = 0; jt < 4; ++jt) {
                int r = jt * 10 + k;                 // 0..79
                int ad = xbase + r + ((r >= thresh) ? 2 : 0);
                xv[jt] = *(const float2*)&xs_s[cur][ad];
            }
            float wk[8]  = {w00.x, w00.y, w00.z, w00.w, w01.x, w01.y, w01.z, w01.w};
            float wk1[8] = {w10.x, w10.y, w10.z, w10.w, w11.x, w11.y, w11.z, w11.w};
#pragma unroll
            for (int jo = 0; jo < 8; ++jo)
#pragma unroll
                for (int jt = 0; jt < 4; ++jt)
                    acc[jo][jt] = fmaf(wk1[jo], xv[jt].y, fmaf(wk[jo], xv[jt].x, acc[jo][jt]));
        }
    }

    float bias[8];
#pragma unroll
    for (int jo = 0; jo < 8; ++jo) bias[jo] = b1[oc0 + jo];

    bool tvalid = (t0 + lt0) <= (T1 - 4);
    float psum[8], psq[8];
#pragma unroll
    for (int jo = 0; jo < 8; ++jo) {
        float s = 0.f, q = 0.f;
        if (tvalid) {
            float tmp[4];
#pragma unroll
            for (int jt = 0; jt < 4; ++jt) {
                float v = acc[jo][jt] + bias[jo];
                tmp[jt] = v; s += v; q = fmaf(v, v, q);
            }
            float* yrow = y1 + (size_t)(b * 32 + oc0 + jo) * T1 + t0 + lt0;
            float4 o0; o0.x = tmp[0]; o0.y = tmp[1]; o0.z = tmp[2]; o0.w = tmp[3];
            *(float4*)yrow = o0;
        }
        psum[jo] = s; psq[jo] = q;
    }
#pragma unroll
    for (int off = 32; off >= 4; off >>= 1) {
#pragma unroll
        for (int jo = 0; jo < 8; ++jo) {
            psum[jo] += __shfl_down(psum[jo], off, 64);
            psq[jo]  += __shfl_down(psq[jo],  off, 64);
        }
    }
    int lane = tid & 63, wvi = tid >> 6;      // 4 waves
    if (lane < 4) {
#pragma unroll
        for (int jo = 0; jo < 8; ++jo) {
            sred[((wvi * 4 + lane) * 8 + jo) * 2 + 0] = psum[jo];
            sred[((wvi * 4 + lane) * 8 + jo) * 2 + 1] = psq[jo];
        }
    }
    __syncthreads();
    if (tid < 64) {
        int oc = tid >> 1, which = tid & 1;
        int og = oc >> 3, jo = oc & 7;
        float v = 0.f;
#pragma unroll
        for (int w = 0; w < 4; ++w)
            v += sred[((w * 4 + og) * 8 + jo) * 2 + which];
        atomicAdd(&stats[which * 32 + oc], v);
    }
}

// ---------------- conv2 (BN1+ReLU folded at stage time) + BN2 stats ----------------
// grid 512 (b). block 192: ocg=tid&7 (4 oc each), tg=tid>>3 (4 t each)
// BN1 scale/shift computed in-block from raw stats (bnstats kernel removed).
// Double-buffered staging with register prefetch: y1/weight loads for ic+1
// overlap ic's compute (previous version exposed full global latency 32x/block).
__global__ __launch_bounds__(192, 2) void conv2_kernel(const float* __restrict__ b2,
                                                       const float* __restrict__ g1,
                                                       const float* __restrict__ be1,
                                                       float* __restrict__ ws) {
    const float* w2p = ws + OFS_W2P;
    const float* y1 = ws + OFS_Y1;
    float* y2 = ws + OFS_Y2;
    float* stats = ws + OFS_STATS;
    int b = blockIdx.x;
    int tid = threadIdx.x;
    int ocg = tid & 7, tg = tid >> 3;
    int oc0 = ocg * 4, lt0 = tg * 4;

    __shared__ __align__(16) float a1s[2][500];
    __shared__ __align__(16) float w2s[2][800];   // [k][oc] 25*32
    __shared__ float sred[192];
    __shared__ float bns[64];                     // BN1 scale/shift

    if (tid < 32) {
        float mean = stats[tid] * (1.f / 253952.f);
        float var  = stats[32 + tid] * (1.f / 253952.f) - mean * mean;
        float s = g1[tid] * rsqrtf(var + 1e-5f);
        bns[tid]      = s;
        bns[32 + tid] = be1[tid] - mean * s;
    }

    float acc[4][4];
#pragma unroll
    for (int a = 0; a < 4; ++a)
#pragma unroll
        for (int c = 0; c < 4; ++c) acc[a][c] = 0.f;

    float4 py, pw0, pw1;
    auto fetch = [&](int ic) {
        const float* yrow = y1 + (size_t)(b * 32 + ic) * T1;
        if (tid < 124) py = *(const float4*)(yrow + 4 * tid);
        pw0 = *(const float4*)(w2p + ic * 800 + 4 * tid);           // tid < 192 < 200
        if (tid < 8) pw1 = *(const float4*)(w2p + ic * 800 + 4 * (tid + 192));
    };

    fetch(0);
    for (int ic = 0; ic < 32; ++ic) {
        int cur = ic & 1;
        __syncthreads();                      // buf[cur] free; bns ready (ic==0)
        if (tid < 124) {
            float s1 = bns[ic], sh1 = bns[32 + ic];
            float4 v = py;
            v.x = fmaxf(fmaf(v.x, s1, sh1), 0.f);
            v.y = fmaxf(fmaf(v.y, s1, sh1), 0.f);
            v.z = fmaxf(fmaf(v.z, s1, sh1), 0.f);
            v.w = fmaxf(fmaf(v.w, s1, sh1), 0.f);
            *(float4*)&a1s[cur][4 * tid] = v;
        }
        *(float4*)&w2s[cur][4 * tid] = pw0;
        if (tid < 8) *(float4*)&w2s[cur][4 * (tid + 192)] = pw1;
        if (ic + 1 < 32) fetch(ic + 1);       // global loads fly during compute
        __syncthreads();

#pragma unroll 1
        for (int kp = 0; kp < 12; ++kp) {
            const int k = kp * 2;
            float4 wA = *(const float4*)&w2s[cur][k * 32 + oc0];        // tap k
            float4 wB = *(const float4*)&w2s[cur][(k + 1) * 32 + oc0];  // tap k+1
            float x0[4], x1[4];
#pragma unroll
            for (int jt = 0; jt < 4; ++jt) {
                int a = 20 * tg + 5 * jt + k;
                x0[jt] = a1s[cur][a]; x1[jt] = a1s[cur][a + 1];
            }
            float wk[4]  = {wA.x, wA.y, wA.z, wA.w};
            float wk1[4] = {wB.x, wB.y, wB.z, wB.w};
#pragma unroll
            for (int jo = 0; jo < 4; ++jo)
#pragma unroll
                for (int jt = 0; jt < 4; ++jt)
                    acc[jo][jt] = fmaf(wk1[jo], x1[jt], fmaf(wk[jo], x0[jt], acc[jo][jt]));
        }
        // k = 24 tail
        float4 wT = *(const float4*)&w2s[cur][24 * 32 + oc0];
        float wt[4] = {wT.x, wT.y, wT.z, wT.w};
#pragma unroll
        for (int jt = 0; jt < 4; ++jt) {
            float xt_ = a1s[cur][20 * tg + 5 * jt + 24];
#pragma unroll
            for (int jo = 0; jo < 4; ++jo) acc[jo][jt] = fmaf(wt[jo], xt_, acc[jo][jt]);
        }
    }

    float bias[4];
#pragma unroll
    for (int jo = 0; jo < 4; ++jo) bias[jo] = b2[oc0 + jo];

    float psum[4], psq[4];
#pragma unroll
    for (int jo = 0; jo < 4; ++jo) {
        float s = 0.f, q = 0.f;
#pragma unroll
        for (int jt = 0; jt < 4; ++jt) {
            int t2 = lt0 + jt;
            if (t2 < T2) {
                float v = acc[jo][jt] + bias[jo];
                y2[(size_t)(b * 32 + oc0 + jo) * T2 + t2] = v;
                s += v; q = fmaf(v, v, q);
            }
        }
        psum[jo] = s; psq[jo] = q;
    }
#pragma unroll
    for (int off = 32; off >= 8; off >>= 1) {
#pragma unroll
        for (int jo = 0; jo < 4; ++jo) {
            psum[jo] += __shfl_down(psum[jo], off, 64);
            psq[jo]  += __shfl_down(psq[jo],  off, 64);
        }
    }
    int lane = tid & 63, wvi = tid >> 6;   // 3 waves
    if (lane < 8) {
#pragma unroll
        for (int jo = 0; jo < 4; ++jo) {
            sred[((wvi * 8 + lane) * 4 + jo) * 2 + 0] = psum[jo];
            sred[((wvi * 8 + lane) * 4 + jo) * 2 + 1] = psq[jo];
        }
    }
    __syncthreads();
    if (tid < 64) {
        int oc = tid >> 1, which = tid & 1;
        int og = oc >> 2, jo = oc & 3;
        float v = 0.f;
#pragma unroll
        for (int w = 0; w < 3; ++w)
            v += sred[((w * 8 + og) * 4 + jo) * 2 + which];
        atomicAdd(&stats[64 + which * 32 + oc], v);
    }
}

// ---------------- projection + LayerNorm, writes xs[t][b][l] ----------------
// BN2 scale/shift computed in-block from raw stats (bnstats kernel removed).
__global__ __launch_bounds__(256, 2) void proj_kernel(const float* __restrict__ g2,
                                                      const float* __restrict__ be2,
                                                      const float* __restrict__ pw,
                                                      const float* __restrict__ pb,
                                                      const float* __restrict__ lng,
                                                      const float* __restrict__ lnb,
                                                      float* __restrict__ ws) {
    int b = blockIdx.x;
    int tid = threadIdx.x;
    __shared__ float a2s[3040];       // [f][t]
    __shared__ float pws[1056];       // [l][33]
    __shared__ float bns2[64];
    const float* stats = ws + OFS_STATS;
    const float* y2 = ws + OFS_Y2 + (size_t)b * (32 * T2);
    float* xsg = ws + OFS_XS;

    if (tid < 32) {
        float mean = stats[64 + tid] * (1.f / 48640.f);
        float var  = stats[96 + tid] * (1.f / 48640.f) - mean * mean;
        float s = g2[tid] * rsqrtf(var + 1e-5f);
        bns2[tid]      = s;
        bns2[32 + tid] = be2[tid] - mean * s;
    }
    __syncthreads();

    for (int f = 0; f < 32; ++f) {
        float s2  = bns2[f];
        float sh2 = bns2[32 + f];
        if (tid < T2)
            a2s[f * T2 + tid] = fmaxf(fmaf(y2[f * T2 + tid], s2, sh2), 0.f);
    }
    for (int i = tid; i < 1024; i += 256)
        pws[(i >> 5) * 33 + (i & 31)] = pw[i];

    int l = tid & 31, ts = tid >> 5;
    float pbv = pb[l], lg = lng[l], lb = lnb[l];
    __syncthreads();

    for (int it = 0; it < 12; ++it) {
        int t = ts + 8 * it;
        if (t < T2) {
            float v = pbv;
#pragma unroll
            for (int f = 0; f < 32; ++f)
                v = fmaf(a2s[f * T2 + t], pws[l * 33 + f], v);
            float sum = v;
#pragma unroll
            for (int off = 16; off >= 1; off >>= 1) sum += __shfl_xor(sum, off, 64);
            float mean = sum * (1.f / 32.f);
            float d = v - mean;
            float q = d * d;
#pragma unroll
            for (int off = 16; off >= 1; off >>= 1) q += __shfl_xor(q, off, 64);
            float o = d * rsqrtf(q * (1.f / 32.f) + 1e-5f) * lg + lb;
            xsg[(size_t)t * (NB * 32) + b * 32 + l] = o;
        }
    }
}

// ---------------- PLRNN scan + pooled mean + output projection ----------------
// grid 512 (b), block 64 (one wave). No register array indexed by runtime value
// (would demote to scratch — R1/R2 lesson). half-dependent slices read from LDS.
__global__ __launch_bounds__(64)
__attribute__((amdgpu_waves_per_eu(1, 1)))
void scan_kernel(const float* __restrict__ Am,
                 const float* __restrict__ Wm,
                 const float* __restrict__ hbp,
                 const float* __restrict__ ow,
                 const float* __restrict__ ob,
                 const float* __restrict__ ws,
                 float* __restrict__ out) {
    int b = blockIdx.x;
    int lane = threadIdx.x;
    int l = lane & 31, half = lane >> 5;
    __shared__ __align__(16) float hs[32];
    __shared__ __align__(16) float hds[64];
    __shared__ float ows[1056];

    float Wc[32], WT[32], Ah[16];
#pragma unroll
    for (int j = 0; j < 32; ++j) Wc[j] = Wm[j * HIDD + lane];          // W[j][lane]
#pragma unroll
    for (int m = 0; m < 32; ++m) WT[m] = Wm[l * HIDD + half * 32 + m]; // W[l][m-half]
#pragma unroll
    for (int j = 0; j < 16; ++j) Ah[j] = Am[l * 32 + half * 16 + j];   // A[l][j-half]
    float hbv = hbp[lane];
    for (int i = lane; i < 1024; i += 64)
        ows[(i >> 5) * 33 + (i & 31)] = ow[i];

    const float* xsg = ws + OFS_XS + b * 32;
    if (lane < 32) hs[l] = 0.f;
    float xv = xsg[l];
    float pool = 0.f;
    __syncthreads();

    for (int t = 0; t < T2; ++t) {
        __syncthreads();
        float4 hv[8];
#pragma unroll
        for (int q = 0; q < 8; ++q) hv[q] = *(const float4*)&hs[4 * q];
        float a0 = hbv, a1 = 0.f, a2 = 0.f, a3 = 0.f;
#pragma unroll
        for (int q = 0; q < 8; ++q) {
            a0 = fmaf(Wc[4 * q + 0], hv[q].x, a0);
            a1 = fmaf(Wc[4 * q + 1], hv[q].y, a1);
            a2 = fmaf(Wc[4 * q + 2], hv[q].z, a2);
            a3 = fmaf(Wc[4 * q + 3], hv[q].w, a3);
        }
        float hid = fmaxf((a0 + a1) + (a2 + a3), 0.f);
        float4 hl[4];
#pragma unroll
        for (int q = 0; q < 4; ++q) hl[q] = *(const float4*)&hs[half * 16 + 4 * q];
        float l0 = 0.f, l1 = 0.f;
#pragma unroll
        for (int q = 0; q < 4; ++q) {
            l0 = fmaf(Ah[4 * q + 0], hl[q].x, l0);
            l1 = fmaf(Ah[4 * q + 1], hl[q].y, l1);
            l0 = fmaf(Ah[4 * q + 2], hl[q].z, l0);
            l1 = fmaf(Ah[4 * q + 3], hl[q].w, l1);
        }
        float lin = l0 + l1;
        hds[lane] = hid;
        __syncthreads();
        float n0 = 0.f, n1 = 0.f, n2 = 0.f, n3 = 0.f;
#pragma unroll
        for (int q = 0; q < 8; ++q) {
            float4 d4 = *(const float4*)&hds[half * 32 + 4 * q];
            n0 = fmaf(WT[4 * q + 0], d4.x, n0);
            n1 = fmaf(WT[4 * q + 1], d4.y, n1);
            n2 = fmaf(WT[4 * q + 2], d4.z, n2);
            n3 = fmaf(WT[4 * q + 3], d4.w, n3);
        }
        float part = (n0 + n1) + (n2 + n3) + lin;
        part += __shfl_xor(part, 32, 64);
        float hnew = part + xv;
        pool += hnew;
        if (t + 1 < T2) xv = xsg[(size_t)(t + 1) * (NB * 32) + l];
        if (lane < 32) hs[l] = hnew;
    }

    __syncthreads();
    if (lane < 32) hs[l] = pool * (1.f / 95.f);
    __syncthreads();
    if (lane < 32) {
        float4 p0 = *(const float4*)&hs[0];
        float4 p1 = *(const float4*)&hs[4];
        float4 p2 = *(const float4*)&hs[8];
        float4 p3 = *(const float4*)&hs[12];
        float4 p4 = *(const float4*)&hs[16];
        float4 p5 = *(const float4*)&hs[20];
        float4 p6 = *(const float4*)&hs[24];
        float4 p7 = *(const float4*)&hs[28];
        float o = ob[l];
        const float* owr = &ows[l * 33];
        o = fmaf(owr[0],  p0.x, o); o = fmaf(owr[1],  p0.y, o);
        o = fmaf(owr[2],  p0.z, o); o = fmaf(owr[3],  p0.w, o);
        o = fmaf(owr[4],  p1.x, o); o = fmaf(owr[5],  p1.y, o);
        o = fmaf(owr[6],  p1.z, o); o = fmaf(owr[7],  p1.w, o);
        o = fmaf(owr[8],  p2.x, o); o = fmaf(owr[9],  p2.y, o);
        o = fmaf(owr[10], p2.z, o); o = fmaf(owr[11], p2.w, o);
        o = fmaf(owr[12], p3.x, o); o = fmaf(owr[13], p3.y, o);
        o = fmaf(owr[14], p3.z, o); o = fmaf(owr[15], p3.w, o);
        o = fmaf(owr[16], p4.x, o); o = fmaf(owr[17], p4.y, o);
        o = fmaf(owr[18], p4.z, o); o = fmaf(owr[19], p4.w, o);
        o = fmaf(owr[20], p5.x, o); o = fmaf(owr[21], p5.y, o);
        o = fmaf(owr[22], p5.z, o); o = fmaf(owr[23], p5.w, o);
        o = fmaf(owr[24], p6.x, o); o = fmaf(owr[25], p6.y, o);
        o = fmaf(owr[26], p6.z, o); o = fmaf(owr[27], p6.w, o);
        o = fmaf(owr[28], p7.x, o); o = fmaf(owr[29], p7.y, o);
        o = fmaf(owr[30], p7.z, o); o = fmaf(owr[31], p7.w, o);
        out[b * 32 + l] = o;
    }
}

extern "C" void kernel_launch(void* const* d_in, const int* in_sizes, int n_in,
                              void* d_out, int out_size, void* d_ws, size_t ws_size,
                              hipStream_t stream) {
    (void)in_sizes; (void)n_in; (void)out_size; (void)ws_size;
    const float* x   = (const float*)d_in[0];
    const float* w1  = (const float*)d_in[1];
    const float* b1  = (const float*)d_in[2];
    const float* g1  = (const float*)d_in[3];
    const float* be1 = (const float*)d_in[4];
    const float* w2  = (const float*)d_in[5];
    const float* b2  = (const float*)d_in[6];
    const float* g2  = (const float*)d_in[7];
    const float* be2 = (const float*)d_in[8];
    const float* pw  = (const float*)d_in[9];
    const float* pb  = (const float*)d_in[10];
    const float* lng = (const float*)d_in[11];
    const float* lnb = (const float*)d_in[12];
    const float* Am  = (const float*)d_in[13];
    const float* Wm  = (const float*)d_in[14];
    const float* hb  = (const float*)d_in[15];
    const float* ow  = (const float*)d_in[16];
    const float* ob  = (const float*)d_in[17];
    float* ws  = (float*)d_ws;
    float* out = (float*)d_out;

    prep_kernel<<<176, 256, 0, stream>>>(w1, w2, ws);
    conv1_kernel<<<1024, 256, 0, stream>>>(x, b1, ws);
    conv2_kernel<<<512, 192, 0, stream>>>(b2, g1, be1, ws);
    proj_kernel<<<512, 256, 0, stream>>>(g2, be2, pw, pb, lng, lnb, ws);
    scan_kernel<<<512, 64, 0, stream>>>(Am, Wm, hb, ow, ob, ws, out);
}

// Round 2
// 448.772 us; speedup vs baseline: 1.0432x; 1.0212x over previous
//
#include <hip/hip_runtime.h>

#define NB    512
#define CIN   12
#define TIN   5000
#define C1    32
#define T1    496
#define T2    95
#define LATD  32
#define HIDD  64

// workspace layout (float offsets)
#define OFS_STATS 0        // 256 floats
#define OFS_W1P   256      // 12*50*32 = 19200, layout [ic][k][oc]
#define OFS_W2P   19456    // 32*25*32 = 25600, layout [ic][k][oc]
#define OFS_Y1    45056    // 512*32*496 = 8126464
#define OFS_Y2    8171520  // 512*32*95  = 1556480
#define OFS_XS    OFS_Y1   // xs[95][512][32] aliases y1 (y1 dead after conv2)

// ---------------- prep: zero stats + repack weights ----------------
__global__ void prep_kernel(const float* __restrict__ w1, const float* __restrict__ w2,
                            float* __restrict__ ws) {
    int idx = blockIdx.x * 256 + threadIdx.x;
    if (idx < 256) ws[idx] = 0.f;
    int j = idx - 256;
    if (j >= 0 && j < 19200) {            // w1p[ic][k][oc], oc fastest
        int ic = j / 1600, r = j % 1600, k = r / 32, oc = r % 32;
        ws[OFS_W1P + j] = w1[oc * 600 + ic * 50 + k];
    }
    int j2 = idx - 19456;
    if (j2 >= 0 && j2 < 25600) {          // w2p[ic][k][oc]
        int ic = j2 / 800, r = j2 % 800, k = r / 32, oc = r % 32;
        ws[OFS_W2P + j2] = w2[oc * 800 + ic * 25 + k];
    }
}

// ---------------- conv1 + bias, fused BN1 stats ----------------
// grid 1024: b = bx>>1, t-tile (256) = bx&1. block 256: ocg=tid&7 (4 oc), tg=tid>>3 (8 t)
// R1 post-mortem: 4-t tiles broke the conflict-free 82-stride geometry (bank residues
// 41tg-(tg&1) alias 2-way -> SQ_LDS_BANK_CONFLICT 0.79M->10.7M) and doubled weight
// ds_read_b128 traffic. This version keeps 16 waves/CU (4/SIMD) but restores the
// proven 8-t / 82-stride windows: per-wave x reads hit banks 18*tg mod 32 =
// {0,18,4,22,8,26,12,30} (conflict-free), weight b128 reads cover banks 0..31 once
// (broadcast x8, conflict-free). Pad threshold r>=80 is wave-uniform -> SALU select.
__global__ __launch_bounds__(256, 4) void conv1_kernel(const float* __restrict__ x,
                                                       const float* __restrict__ b1,
                                                       float* __restrict__ ws) {
    const float* w1p = ws + OFS_W1P;
    float* y1 = ws + OFS_Y1;
    float* stats = ws + OFS_STATS;
    int b  = blockIdx.x >> 1;
    int t0 = (blockIdx.x & 1) * 256;
    int tid = threadIdx.x;
    int ocg = tid & 7, tg = tid >> 3;         // 8 ocg x 32 tg
    int oc0 = ocg * 4, lt0 = tg * 8;
    int xbase = 82 * tg;                      // skewed LDS base (conflict-free reads)

    __shared__ __align__(16) float xs_s[2][2664];   // 2600 + skew, double-buffered
    __shared__ __align__(16) float ws_s[2][1600];   // [k][oc] 50*32
    __shared__ float sred[256];

    float acc[4][8];
#pragma unroll
    for (int a = 0; a < 4; ++a)
#pragma unroll
        for (int c = 0; c < 8; ++c) acc[a][c] = 0.f;

    const float* xb = x + (size_t)b * (CIN * TIN) + t0 * 10;
    int nvalid = TIN - t0 * 10;               // 5000 or 2440

    float4 px[3];
    float4 pw[2];

    auto fetch = [&](int ic) {
#pragma unroll
        for (int j = 0; j < 3; ++j) {
            int i = tid + j * 256;
            if (i < 650) {
                int src = 4 * i;
                const float* gp = xb + ic * TIN + src;
                float4 v;
                if (src + 4 <= nvalid) {
                    v = *(const float4*)gp;
                } else {
                    v.x = (src + 0 < nvalid) ? gp[0] : 0.f;
                    v.y = (src + 1 < nvalid) ? gp[1] : 0.f;
                    v.z = (src + 2 < nvalid) ? gp[2] : 0.f;
                    v.w = (src + 3 < nvalid) ? gp[3] : 0.f;
                }
                px[j] = v;
            }
        }
#pragma unroll
        for (int j = 0; j < 2; ++j) {
            int i = tid + j * 256;
            if (i < 400) pw[j] = *(const float4*)(w1p + ic * 1600 + 4 * i);
        }
    };

    fetch(0);
    for (int ic = 0; ic < CIN; ++ic) {
        int cur = ic & 1;
        __syncthreads();                      // buf[cur] free (read 2 iters ago)
#pragma unroll
        for (int j = 0; j < 3; ++j) {
            int i = tid + j * 256;
            if (i < 650) {
                int src = 4 * i;
                int dst = src + (i / 20) * 2; // skew +2 per 80 words
                float2 lo; lo.x = px[j].x; lo.y = px[j].y;
                float2 hi; hi.x = px[j].z; hi.y = px[j].w;
                *(float2*)&xs_s[cur][dst]     = lo;
                *(float2*)&xs_s[cur][dst + 2] = hi;
            }
        }
#pragma unroll
        for (int j = 0; j < 2; ++j) {
            int i = tid + j * 256;
            if (i < 400) *(float4*)&ws_s[cur][4 * i] = pw[j];
        }
        if (ic + 1 < CIN) fetch(ic + 1);      // global loads fly during compute
        __syncthreads();

#pragma unroll 1
        for (int kp = 0; kp < 25; ++kp) {
            const int k = kp * 2;
            const float* wr = &ws_s[cur][k * 32 + oc0];
            float4 w00 = *(const float4*)wr;         // tap k,   oc0..oc0+3
            float4 w10 = *(const float4*)(wr + 32);  // tap k+1, oc0..oc0+3
            float2 xv[8];
#pragma unroll
            for (int jt = 0; jt < 8; ++jt) {
                int r = jt * 10 + k;                 // 0..118, uniform across lanes
                int ad = xbase + r + ((r >= 80) ? 2 : 0);
                xv[jt] = *(const float2*)&xs_s[cur][ad];
            }
            float wk[4]  = {w00.x, w00.y, w00.z, w00.w};
            float wk1[4] = {w10.x, w10.y, w10.z, w10.w};
#pragma unroll
            for (int jo = 0; jo < 4; ++jo)
#pragma unroll
                for (int jt = 0; jt < 8; ++jt)
                    acc[jo][jt] = fmaf(wk1[jo], xv[jt].y, fmaf(wk[jo], xv[jt].x, acc[jo][jt]));
        }
    }

    float bias[4];
#pragma unroll
    for (int jo = 0; jo < 4; ++jo) bias[jo] = b1[oc0 + jo];

    bool tvalid = (t0 + lt0) <= (T1 - 8);
    float psum[4], psq[4];
#pragma unroll
    for (int jo = 0; jo < 4; ++jo) {
        float s = 0.f, q = 0.f;
        if (tvalid) {
            float tmp[8];
#pragma unroll
            for (int jt = 0; jt < 8; ++jt) {
                float v = acc[jo][jt] + bias[jo];
                tmp[jt] = v; s += v; q = fmaf(v, v, q);
            }
            float* yrow = y1 + (size_t)(b * 32 + oc0 + jo) * T1 + t0 + lt0;
            float4 o0; o0.x = tmp[0]; o0.y = tmp[1]; o0.z = tmp[2]; o0.w = tmp[3];
            float4 o1; o1.x = tmp[4]; o1.y = tmp[5]; o1.z = tmp[6]; o1.w = tmp[7];
            *(float4*)yrow       = o0;
            *(float4*)(yrow + 4) = o1;
        }
        psum[jo] = s; psq[jo] = q;
    }
    // reduce over tg within wave: lanes with same ocg are lane = ocg + 8*m
#pragma unroll
    for (int off = 32; off >= 8; off >>= 1) {
#pragma unroll
        for (int jo = 0; jo < 4; ++jo) {
            psum[jo] += __shfl_down(psum[jo], off, 64);
            psq[jo]  += __shfl_down(psq[jo],  off, 64);
        }
    }
    int lane = tid & 63, wvi = tid >> 6;      // 4 waves
    if (lane < 8) {
#pragma unroll
        for (int jo = 0; jo < 4; ++jo) {
            sred[((wvi * 8 + lane) * 4 + jo) * 2 + 0] = psum[jo];
            sred[((wvi * 8 + lane) * 4 + jo) * 2 + 1] = psq[jo];
        }
    }
    __syncthreads();
    if (tid < 64) {
        int oc = tid >> 1, which = tid & 1;
        int og = oc >> 2, jo = oc & 3;        // oc = 4*ocg + jo
        float v = 0.f;
#pragma unroll
        for (int w = 0; w < 4; ++w)
            v += sred[((w * 8 + og) * 4 + jo) * 2 + which];
        atomicAdd(&stats[which * 32 + oc], v);
    }
}

// ---------------- conv2 (BN1+ReLU folded at stage time) + BN2 stats ----------------
// grid 512 (b). block 192: ocg=tid&7 (4 oc each), tg=tid>>3 (4 t each)
// BN1 scale/shift computed in-block from raw stats (bnstats kernel removed).
// Double-buffered staging with register prefetch: y1/weight loads for ic+1
// overlap ic's compute.
__global__ __launch_bounds__(192, 2) void conv2_kernel(const float* __restrict__ b2,
                                                       const float* __restrict__ g1,
                                                       const float* __restrict__ be1,
                                                       float* __restrict__ ws) {
    const float* w2p = ws + OFS_W2P;
    const float* y1 = ws + OFS_Y1;
    float* y2 = ws + OFS_Y2;
    float* stats = ws + OFS_STATS;
    int b = blockIdx.x;
    int tid = threadIdx.x;
    int ocg = tid & 7, tg = tid >> 3;
    int oc0 = ocg * 4, lt0 = tg * 4;

    __shared__ __align__(16) float a1s[2][500];
    __shared__ __align__(16) float w2s[2][800];   // [k][oc] 25*32
    __shared__ float sred[192];
    __shared__ float bns[64];                     // BN1 scale/shift

    if (tid < 32) {
        float mean = stats[tid] * (1.f / 253952.f);
        float var  = stats[32 + tid] * (1.f / 253952.f) - mean * mean;
        float s = g1[tid] * rsqrtf(var + 1e-5f);
        bns[tid]      = s;
        bns[32 + tid] = be1[tid] - mean * s;
    }

    float acc[4][4];
#pragma unroll
    for (int a = 0; a < 4; ++a)
#pragma unroll
        for (int c = 0; c < 4; ++c) acc[a][c] = 0.f;

    float4 py, pw0, pw1;
    auto fetch = [&](int ic) {
        const float* yrow = y1 + (size_t)(b * 32 + ic) * T1;
        if (tid < 124) py = *(const float4*)(yrow + 4 * tid);
        pw0 = *(const float4*)(w2p + ic * 800 + 4 * tid);           // tid < 192 < 200
        if (tid < 8) pw1 = *(const float4*)(w2p + ic * 800 + 4 * (tid + 192));
    };

    fetch(0);
    for (int ic = 0; ic < 32; ++ic) {
        int cur = ic & 1;
        __syncthreads();                      // buf[cur] free; bns ready (ic==0)
        if (tid < 124) {
            float s1 = bns[ic], sh1 = bns[32 + ic];
            float4 v = py;
            v.x = fmaxf(fmaf(v.x, s1, sh1), 0.f);
            v.y = fmaxf(fmaf(v.y, s1, sh1), 0.f);
            v.z = fmaxf(fmaf(v.z, s1, sh1), 0.f);
            v.w = fmaxf(fmaf(v.w, s1, sh1), 0.f);
            *(float4*)&a1s[cur][4 * tid] = v;
        }
        *(float4*)&w2s[cur][4 * tid] = pw0;
        if (tid < 8) *(float4*)&w2s[cur][4 * (tid + 192)] = pw1;
        if (ic + 1 < 32) fetch(ic + 1);       // global loads fly during compute
        __syncthreads();

#pragma unroll 1
        for (int kp = 0; kp < 12; ++kp) {
            const int k = kp * 2;
            float4 wA = *(const float4*)&w2s[cur][k * 32 + oc0];        // tap k
            float4 wB = *(const float4*)&w2s[cur][(k + 1) * 32 + oc0];  // tap k+1
            float x0[4], x1[4];
#pragma unroll
            for (int jt = 0; jt < 4; ++jt) {
                int a = 20 * tg + 5 * jt + k;
                x0[jt] = a1s[cur][a]; x1[jt] = a1s[cur][a + 1];
            }
            float wk[4]  = {wA.x, wA.y, wA.z, wA.w};
            float wk1[4] = {wB.x, wB.y, wB.z, wB.w};
#pragma unroll
            for (int jo = 0; jo < 4; ++jo)
#pragma unroll
                for (int jt = 0; jt < 4; ++jt)
                    acc[jo][jt] = fmaf(wk1[jo], x1[jt], fmaf(wk[jo], x0[jt], acc[jo][jt]));
        }
        // k = 24 tail
        float4 wT = *(const float4*)&w2s[cur][24 * 32 + oc0];
        float wt[4] = {wT.x, wT.y, wT.z, wT.w};
#pragma unroll
        for (int jt = 0; jt < 4; ++jt) {
            float xt_ = a1s[cur][20 * tg + 5 * jt + 24];
#pragma unroll
            for (int jo = 0; jo < 4; ++jo) acc[jo][jt] = fmaf(wt[jo], xt_, acc[jo][jt]);
        }
    }

    float bias[4];
#pragma unroll
    for (int jo = 0; jo < 4; ++jo) bias[jo] = b2[oc0 + jo];

    float psum[4], psq[4];
#pragma unroll
    for (int jo = 0; jo < 4; ++jo) {
        float s = 0.f, q = 0.f;
#pragma unroll
        for (int jt = 0; jt < 4; ++jt) {
            int t2 = lt0 + jt;
            if (t2 < T2) {
                float v = acc[jo][jt] + bias[jo];
                y2[(size_t)(b * 32 + oc0 + jo) * T2 + t2] = v;
                s += v; q = fmaf(v, v, q);
            }
        }
        psum[jo] = s; psq[jo] = q;
    }
#pragma unroll
    for (int off = 32; off >= 8; off >>= 1) {
#pragma unroll
        for (int jo = 0; jo < 4; ++jo) {
            psum[jo] += __shfl_down(psum[jo], off, 64);
            psq[jo]  += __shfl_down(psq[jo],  off, 64);
        }
    }
    int lane = tid & 63, wvi = tid >> 6;   // 3 waves
    if (lane < 8) {
#pragma unroll
        for (int jo = 0; jo < 4; ++jo) {
            sred[((wvi * 8 + lane) * 4 + jo) * 2 + 0] = psum[jo];
            sred[((wvi * 8 + lane) * 4 + jo) * 2 + 1] = psq[jo];
        }
    }
    __syncthreads();
    if (tid < 64) {
        int oc = tid >> 1, which = tid & 1;
        int og = oc >> 2, jo = oc & 3;
        float v = 0.f;
#pragma unroll
        for (int w = 0; w < 3; ++w)
            v += sred[((w * 8 + og) * 4 + jo) * 2 + which];
        atomicAdd(&stats[64 + which * 32 + oc], v);
    }
}

// ---------------- projection + LayerNorm, writes xs[t][b][l] ----------------
// BN2 scale/shift computed in-block from raw stats (bnstats kernel removed).
__global__ __launch_bounds__(256, 2) void proj_kernel(const float* __restrict__ g2,
                                                      const float* __restrict__ be2,
                                                      const float* __restrict__ pw,
                                                      const float* __restrict__ pb,
                                                      const float* __restrict__ lng,
                                                      const float* __restrict__ lnb,
                                                      float* __restrict__ ws) {
    int b = blockIdx.x;
    int tid = threadIdx.x;
    __shared__ float a2s[3040];       // [f][t]
    __shared__ float pws[1056];       // [l][33]
    __shared__ float bns2[64];
    const float* stats = ws + OFS_STATS;
    const float* y2 = ws + OFS_Y2 + (size_t)b * (32 * T2);
    float* xsg = ws + OFS_XS;

    if (tid < 32) {
        float mean = stats[64 + tid] * (1.f / 48640.f);
        float var  = stats[96 + tid] * (1.f / 48640.f) - mean * mean;
        float s = g2[tid] * rsqrtf(var + 1e-5f);
        bns2[tid]      = s;
        bns2[32 + tid] = be2[tid] - mean * s;
    }
    __syncthreads();

    for (int f = 0; f < 32; ++f) {
        float s2  = bns2[f];
        float sh2 = bns2[32 + f];
        if (tid < T2)
            a2s[f * T2 + tid] = fmaxf(fmaf(y2[f * T2 + tid], s2, sh2), 0.f);
    }
    for (int i = tid; i < 1024; i += 256)
        pws[(i >> 5) * 33 + (i & 31)] = pw[i];

    int l = tid & 31, ts = tid >> 5;
    float pbv = pb[l], lg = lng[l], lb = lnb[l];
    __syncthreads();

    for (int it = 0; it < 12; ++it) {
        int t = ts + 8 * it;
        if (t < T2) {
            float v = pbv;
#pragma unroll
            for (int f = 0; f < 32; ++f)
                v = fmaf(a2s[f * T2 + t], pws[l * 33 + f], v);
            float sum = v;
#pragma unroll
            for (int off = 16; off >= 1; off >>= 1) sum += __shfl_xor(sum, off, 64);
            float mean = sum * (1.f / 32.f);
            float d = v - mean;
            float q = d * d;
#pragma unroll
            for (int off = 16; off >= 1; off >>= 1) q += __shfl_xor(q, off, 64);
            float o = d * rsqrtf(q * (1.f / 32.f) + 1e-5f) * lg + lb;
            xsg[(size_t)t * (NB * 32) + b * 32 + l] = o;
        }
    }
}

// ---------------- PLRNN scan + pooled mean + output projection ----------------
// grid 512 (b), block 64 (one wave). No register array indexed by runtime value
// (would demote to scratch — R1/R2 lesson). half-dependent slices read from LDS.
__global__ __launch_bounds__(64)
__attribute__((amdgpu_waves_per_eu(1, 1)))
void scan_kernel(const float* __restrict__ Am,
                 const float* __restrict__ Wm,
                 const float* __restrict__ hbp,
                 const float* __restrict__ ow,
                 const float* __restrict__ ob,
                 const float* __restrict__ ws,
                 float* __restrict__ out) {
    int b = blockIdx.x;
    int lane = threadIdx.x;
    int l = lane & 31, half = lane >> 5;
    __shared__ __align__(16) float hs[32];
    __shared__ __align__(16) float hds[64];
    __shared__ float ows[1056];

    float Wc[32], WT[32], Ah[16];
#pragma unroll
    for (int j = 0; j < 32; ++j) Wc[j] = Wm[j * HIDD + lane];          // W[j][lane]
#pragma unroll
    for (int m = 0; m < 32; ++m) WT[m] = Wm[l * HIDD + half * 32 + m]; // W[l][m-half]
#pragma unroll
    for (int j = 0; j < 16; ++j) Ah[j] = Am[l * 32 + half * 16 + j];   // A[l][j-half]
    float hbv = hbp[lane];
    for (int i = lane; i < 1024; i += 64)
        ows[(i >> 5) * 33 + (i & 31)] = ow[i];

    const float* xsg = ws + OFS_XS + b * 32;
    if (lane < 32) hs[l] = 0.f;
    float xv = xsg[l];
    float pool = 0.f;
    __syncthreads();

    for (int t = 0; t < T2; ++t) {
        __syncthreads();
        float4 hv[8];
#pragma unroll
        for (int q = 0; q < 8; ++q) hv[q] = *(const float4*)&hs[4 * q];
        float a0 = hbv, a1 = 0.f, a2 = 0.f, a3 = 0.f;
#pragma unroll
        for (int q = 0; q < 8; ++q) {
            a0 = fmaf(Wc[4 * q + 0], hv[q].x, a0);
            a1 = fmaf(Wc[4 * q + 1], hv[q].y, a1);
            a2 = fmaf(Wc[4 * q + 2], hv[q].z, a2);
            a3 = fmaf(Wc[4 * q + 3], hv[q].w, a3);
        }
        float hid = fmaxf((a0 + a1) + (a2 + a3), 0.f);
        float4 hl[4];
#pragma unroll
        for (int q = 0; q < 4; ++q) hl[q] = *(const float4*)&hs[half * 16 + 4 * q];
        float l0 = 0.f, l1 = 0.f;
#pragma unroll
        for (int q = 0; q < 4; ++q) {
            l0 = fmaf(Ah[4 * q + 0], hl[q].x, l0);
            l1 = fmaf(Ah[4 * q + 1], hl[q].y, l1);
            l0 = fmaf(Ah[4 * q + 2], hl[q].z, l0);
            l1 = fmaf(Ah[4 * q + 3], hl[q].w, l1);
        }
        float lin = l0 + l1;
        hds[lane] = hid;
        __syncthreads();
        float n0 = 0.f, n1 = 0.f, n2 = 0.f, n3 = 0.f;
#pragma unroll
        for (int q = 0; q < 8; ++q) {
            float4 d4 = *(const float4*)&hds[half * 32 + 4 * q];
            n0 = fmaf(WT[4 * q + 0], d4.x, n0);
            n1 = fmaf(WT[4 * q + 1], d4.y, n1);
            n2 = fmaf(WT[4 * q + 2], d4.z, n2);
            n3 = fmaf(WT[4 * q + 3], d4.w, n3);
        }
        float part = (n0 + n1) + (n2 + n3) + lin;
        part += __shfl_xor(part, 32, 64);
        float hnew = part + xv;
        pool += hnew;
        if (t + 1 < T2) xv = xsg[(size_t)(t + 1) * (NB * 32) + l];
        if (lane < 32) hs[l] = hnew;
    }

    __syncthreads();
    if (lane < 32) hs[l] = pool * (1.f / 95.f);
    __syncthreads();
    if (lane < 32) {
        float4 p0 = *(const float4*)&hs[0];
        float4 p1 = *(const float4*)&hs[4];
        float4 p2 = *(const float4*)&hs[8];
        float4 p3 = *(const float4*)&hs[12];
        float4 p4 = *(const float4*)&hs[16];
        float4 p5 = *(const float4*)&hs[20];
        float4 p6 = *(const float4*)&hs[24];
        float4 p7 = *(const float4*)&hs[28];
        float o = ob[l];
        const float* owr = &ows[l * 33];
        o = fmaf(owr[0],  p0.x, o); o = fmaf(owr[1],  p0.y, o);
        o = fmaf(owr[2],  p0.z, o); o = fmaf(owr[3],  p0.w, o);
        o = fmaf(owr[4],  p1.x, o); o = fmaf(owr[5],  p1.y, o);
        o = fmaf(owr[6],  p1.z, o); o = fmaf(owr[7],  p1.w, o);
        o = fmaf(owr[8],  p2.x, o); o = fmaf(owr[9],  p2.y, o);
        o = fmaf(owr[10], p2.z, o); o = fmaf(owr[11], p2.w, o);
        o = fmaf(owr[12], p3.x, o); o = fmaf(owr[13], p3.y, o);
        o = fmaf(owr[14], p3.z, o); o = fmaf(owr[15], p3.w, o);
        o = fmaf(owr[16], p4.x, o); o = fmaf(owr[17], p4.y, o);
        o = fmaf(owr[18], p4.z, o); o = fmaf(owr[19], p4.w, o);
        o = fmaf(owr[20], p5.x, o); o = fmaf(owr[21], p5.y, o);
        o = fmaf(owr[22], p5.z, o); o = fmaf(owr[23], p5.w, o);
        o = fmaf(owr[24], p6.x, o); o = fmaf(owr[25], p6.y, o);
        o = fmaf(owr[26], p6.z, o); o = fmaf(owr[27], p6.w, o);
        o = fmaf(owr[28], p7.x, o); o = fmaf(owr[29], p7.y, o);
        o = fmaf(owr[30], p7.z, o); o = fmaf(owr[31], p7.w, o);
        out[b * 32 + l] = o;
    }
}

extern "C" void kernel_launch(void* const* d_in, const int* in_sizes, int n_in,
                              void* d_out, int out_size, void* d_ws, size_t ws_size,
                              hipStream_t stream) {
    (void)in_sizes; (void)n_in; (void)out_size; (void)ws_size;
    const float* x   = (const float*)d_in[0];
    const float* w1  = (const float*)d_in[1];
    const float* b1  = (const float*)d_in[2];
    const float* g1  = (const float*)d_in[3];
    const float* be1 = (const float*)d_in[4];
    const float* w2  = (const float*)d_in[5];
    const float* b2  = (const float*)d_in[6];
    const float* g2  = (const float*)d_in[7];
    const float* be2 = (const float*)d_in[8];
    const float* pw  = (const float*)d_in[9];
    const float* pb  = (const float*)d_in[10];
    const float* lng = (const float*)d_in[11];
    const float* lnb = (const float*)d_in[12];
    const float* Am  = (const float*)d_in[13];
    const float* Wm  = (const float*)d_in[14];
    const float* hb  = (const float*)d_in[15];
    const float* ow  = (const float*)d_in[16];
    const float* ob  = (const float*)d_in[17];
    float* ws  = (float*)d_ws;
    float* out = (float*)d_out;

    prep_kernel<<<176, 256, 0, stream>>>(w1, w2, ws);
    conv1_kernel<<<1024, 256, 0, stream>>>(x, b1, ws);
    conv2_kernel<<<512, 192, 0, stream>>>(b2, g1, be1, ws);
    proj_kernel<<<512, 256, 0, stream>>>(g2, be2, pw, pb, lng, lnb, ws);
    scan_kernel<<<512, 64, 0, stream>>>(Am, Wm, hb, ow, ob, ws, out);
}

// Round 3
// 418.701 us; speedup vs baseline: 1.1181x; 1.0718x over previous
//
#include <hip/hip_runtime.h>

#define NB    512
#define CIN   12
#define TIN   5000
#define C1    32
#define T1    496
#define T2    95
#define LATD  32
#define HIDD  64

// workspace layout (float offsets)
#define OFS_STATS 0        // 256 floats
#define OFS_W1P   256      // 12*50*32 = 19200, layout [ic][p][j][oc] (polyphase)
#define OFS_W2P   19456    // 32*25*32 = 25600, layout [ic][p][j][oc] (polyphase)
#define OFS_Y1    45056    // 512*32*496 = 8126464
#define OFS_Y2    8171520  // 512*32*95  = 1556480
#define OFS_XS    OFS_Y1   // xs[95][512][32] aliases y1 (y1 dead after conv2)

// ---------------- prep: zero stats + repack weights (polyphase) ----------------
// conv1: k = 10*j + p  -> w1p[ic][p][j][oc]
// conv2: k = 5*j + p   -> w2p[ic][p][j][oc]
__global__ void prep_kernel(const float* __restrict__ w1, const float* __restrict__ w2,
                            float* __restrict__ ws) {
    int idx = blockIdx.x * 256 + threadIdx.x;
    if (idx < 256) ws[idx] = 0.f;
    int j = idx - 256;
    if (j >= 0 && j < 19200) {            // [ic][p][j][oc], oc fastest
        int ic = j / 1600, r = j % 1600;
        int p = r / 160, rr = r % 160, jj = rr / 32, oc = rr % 32;
        ws[OFS_W1P + j] = w1[oc * 600 + ic * 50 + 10 * jj + p];
    }
    int j2 = idx - 19456;
    if (j2 >= 0 && j2 < 25600) {
        int ic = j2 / 800, r = j2 % 800;
        int p = r / 160, rr = r % 160, jj = rr / 32, oc = rr % 32;
        ws[OFS_W2P + j2] = w2[oc * 800 + ic * 25 + 5 * jj + p];
    }
}

// ---------------- conv1 + bias, fused BN1 stats (polyphase) ----------------
// grid 1024: b = bx>>1, t-tile (256) = bx&1. block 256: ocg=tid&7 (4 oc), tg=tid>>3 (8 t)
// R2 post-mortem: conflict-free + 16 waves/CU changed nothing (183us) -> issue-bound
// on non-FMA work (76% FMA density; 8 b64 LDS reads per 64 FMAs + per-kp waits).
// Polyphase: x stored [phase][col] (xsp[p][c] = win[10c+p]); each thread's 8t x 5tap
// window per phase = 12 consecutive floats = 3 ds_read_b128. LDS reads/thread/ic:
// 250 -> 80 instrs, FMAs unchanged, ~93% FMA density. Reads: 8 addrs spaced 8 words
// -> worst 2-way bank alias (free, m136); weight reads cover 32 banks once.
__global__ __launch_bounds__(256, 4) void conv1_kernel(const float* __restrict__ x,
                                                       const float* __restrict__ b1,
                                                       float* __restrict__ ws) {
    const float* w1p = ws + OFS_W1P;
    float* y1 = ws + OFS_Y1;
    float* stats = ws + OFS_STATS;
    int b  = blockIdx.x >> 1;
    int t0 = (blockIdx.x & 1) * 256;
    int tid = threadIdx.x;
    int ocg = tid & 7, tg = tid >> 3;         // 8 ocg x 32 tg
    int oc0 = ocg * 4, lt0 = tg * 8;

    __shared__ __align__(16) float xs_s[2][2680];   // [10][268] polyphase, dbuf
    __shared__ __align__(16) float ws_s[2][1600];   // [p][j][oc] 10*5*32
    __shared__ float sred[256];

    float acc[4][8];
#pragma unroll
    for (int a = 0; a < 4; ++a)
#pragma unroll
        for (int c = 0; c < 8; ++c) acc[a][c] = 0.f;

    const float* xb = x + (size_t)b * (CIN * TIN) + t0 * 10;
    int nvalid = TIN - t0 * 10;               // 5000 or 2440

    float4 px[3];
    float4 pw[2];

    auto fetch = [&](int ic) {
#pragma unroll
        for (int j = 0; j < 3; ++j) {
            int i = tid + j * 256;
            if (i < 650) {
                int src = 4 * i;
                const float* gp = xb + ic * TIN + src;
                float4 v;
                if (src + 4 <= nvalid) {
                    v = *(const float4*)gp;
                } else {
                    v.x = (src + 0 < nvalid) ? gp[0] : 0.f;
                    v.y = (src + 1 < nvalid) ? gp[1] : 0.f;
                    v.z = (src + 2 < nvalid) ? gp[2] : 0.f;
                    v.w = (src + 3 < nvalid) ? gp[3] : 0.f;
                }
                px[j] = v;
            }
        }
#pragma unroll
        for (int j = 0; j < 2; ++j) {
            int i = tid + j * 256;
            if (i < 400) pw[j] = *(const float4*)(w1p + ic * 1600 + 4 * i);
        }
    };

    fetch(0);
    for (int ic = 0; ic < CIN; ++ic) {
        int cur = ic & 1;
        __syncthreads();                      // buf[cur] free (read 2 iters ago)
#pragma unroll
        for (int j = 0; j < 3; ++j) {
            int i = tid + j * 256;
            if (i < 650) {
                int g = 4 * i;                // window position of px[j].x
                int col = g / 10, p = g - 10 * col;
                float vals[4] = {px[j].x, px[j].y, px[j].z, px[j].w};
#pragma unroll
                for (int m = 0; m < 4; ++m) {
                    int pm = p + m;
                    int rr = (pm >= 10) ? pm - 10 : pm;
                    int cc = col + ((pm >= 10) ? 1 : 0);
                    xs_s[cur][rr * 268 + cc] = vals[m];
                }
            }
        }
#pragma unroll
        for (int j = 0; j < 2; ++j) {
            int i = tid + j * 256;
            if (i < 400) *(float4*)&ws_s[cur][4 * i] = pw[j];
        }
        if (ic + 1 < CIN) fetch(ic + 1);      // global loads fly during compute
        __syncthreads();

#pragma unroll 2
        for (int p = 0; p < 10; ++p) {
            const float* xr = &xs_s[cur][p * 268 + 8 * tg];
            float4 xa = *(const float4*)(xr);
            float4 xbv = *(const float4*)(xr + 4);
            float4 xc = *(const float4*)(xr + 8);
            float xv[12] = {xa.x, xa.y, xa.z, xa.w,
                            xbv.x, xbv.y, xbv.z, xbv.w,
                            xc.x, xc.y, xc.z, xc.w};
            const float* wr = &ws_s[cur][p * 160 + oc0];
            float4 w0 = *(const float4*)(wr);
            float4 w1v = *(const float4*)(wr + 32);
            float4 w2v = *(const float4*)(wr + 64);
            float4 w3v = *(const float4*)(wr + 96);
            float4 w4v = *(const float4*)(wr + 128);
            float wj[5][4] = {{w0.x, w0.y, w0.z, w0.w},
                              {w1v.x, w1v.y, w1v.z, w1v.w},
                              {w2v.x, w2v.y, w2v.z, w2v.w},
                              {w3v.x, w3v.y, w3v.z, w3v.w},
                              {w4v.x, w4v.y, w4v.z, w4v.w}};
#pragma unroll
            for (int j = 0; j < 5; ++j)
#pragma unroll
                for (int jt = 0; jt < 8; ++jt) {
                    float xx = xv[jt + j];
#pragma unroll
                    for (int jo = 0; jo < 4; ++jo)
                        acc[jo][jt] = fmaf(wj[j][jo], xx, acc[jo][jt]);
                }
        }
    }

    float bias[4];
#pragma unroll
    for (int jo = 0; jo < 4; ++jo) bias[jo] = b1[oc0 + jo];

    bool tvalid = (t0 + lt0) <= (T1 - 8);
    float psum[4], psq[4];
#pragma unroll
    for (int jo = 0; jo < 4; ++jo) {
        float s = 0.f, q = 0.f;
        if (tvalid) {
            float tmp[8];
#pragma unroll
            for (int jt = 0; jt < 8; ++jt) {
                float v = acc[jo][jt] + bias[jo];
                tmp[jt] = v; s += v; q = fmaf(v, v, q);
            }
            float* yrow = y1 + (size_t)(b * 32 + oc0 + jo) * T1 + t0 + lt0;
            float4 o0; o0.x = tmp[0]; o0.y = tmp[1]; o0.z = tmp[2]; o0.w = tmp[3];
            float4 o1; o1.x = tmp[4]; o1.y = tmp[5]; o1.z = tmp[6]; o1.w = tmp[7];
            *(float4*)yrow       = o0;
            *(float4*)(yrow + 4) = o1;
        }
        psum[jo] = s; psq[jo] = q;
    }
#pragma unroll
    for (int off = 32; off >= 8; off >>= 1) {
#pragma unroll
        for (int jo = 0; jo < 4; ++jo) {
            psum[jo] += __shfl_down(psum[jo], off, 64);
            psq[jo]  += __shfl_down(psq[jo],  off, 64);
        }
    }
    int lane = tid & 63, wvi = tid >> 6;      // 4 waves
    if (lane < 8) {
#pragma unroll
        for (int jo = 0; jo < 4; ++jo) {
            sred[((wvi * 8 + lane) * 4 + jo) * 2 + 0] = psum[jo];
            sred[((wvi * 8 + lane) * 4 + jo) * 2 + 1] = psq[jo];
        }
    }
    __syncthreads();
    if (tid < 64) {
        int oc = tid >> 1, which = tid & 1;
        int og = oc >> 2, jo = oc & 3;        // oc = 4*ocg + jo
        float v = 0.f;
#pragma unroll
        for (int w = 0; w < 4; ++w)
            v += sred[((w * 8 + og) * 4 + jo) * 2 + which];
        atomicAdd(&stats[which * 32 + oc], v);
    }
}

// ---------------- conv2 (BN1+ReLU folded at stage time) + BN2 stats ----------------
// grid 512 (b). block 192: ocg=tid&7 (4 oc each), tg=tid>>3 (4 t each)
// Polyphase (stride 5, K=25 = 5x5 exactly, no tail): a1 stored [5][100]
// (a1p[p][c] = a1[5c+p]); per-phase reads = 2 ds_read_b128 (8 floats), addrs
// 4tg spaced -> all 32 banks once, conflict-free. BN1 scale/shift in-block.
__global__ __launch_bounds__(192, 2) void conv2_kernel(const float* __restrict__ b2,
                                                       const float* __restrict__ g1,
                                                       const float* __restrict__ be1,
                                                       float* __restrict__ ws) {
    const float* w2p = ws + OFS_W2P;
    const float* y1 = ws + OFS_Y1;
    float* y2 = ws + OFS_Y2;
    float* stats = ws + OFS_STATS;
    int b = blockIdx.x;
    int tid = threadIdx.x;
    int ocg = tid & 7, tg = tid >> 3;
    int oc0 = ocg * 4, lt0 = tg * 4;

    __shared__ __align__(16) float a1s[2][500];   // [5][100] polyphase, dbuf
    __shared__ __align__(16) float w2s[2][800];   // [p][j][oc] 5*5*32
    __shared__ float sred[192];
    __shared__ float bns[64];                     // BN1 scale/shift

    if (tid < 32) {
        float mean = stats[tid] * (1.f / 253952.f);
        float var  = stats[32 + tid] * (1.f / 253952.f) - mean * mean;
        float s = g1[tid] * rsqrtf(var + 1e-5f);
        bns[tid]      = s;
        bns[32 + tid] = be1[tid] - mean * s;
    }

    float acc[4][4];
#pragma unroll
    for (int a = 0; a < 4; ++a)
#pragma unroll
        for (int c = 0; c < 4; ++c) acc[a][c] = 0.f;

    float4 py, pw0, pw1;
    auto fetch = [&](int ic) {
        const float* yrow = y1 + (size_t)(b * 32 + ic) * T1;
        if (tid < 124) py = *(const float4*)(yrow + 4 * tid);
        pw0 = *(const float4*)(w2p + ic * 800 + 4 * tid);           // tid < 192 < 200
        if (tid < 8) pw1 = *(const float4*)(w2p + ic * 800 + 4 * (tid + 192));
    };

    fetch(0);
    for (int ic = 0; ic < 32; ++ic) {
        int cur = ic & 1;
        __syncthreads();                      // buf[cur] free; bns ready (ic==0)
        if (tid < 124) {
            float s1 = bns[ic], sh1 = bns[32 + ic];
            float4 v = py;
            float vals[4];
            vals[0] = fmaxf(fmaf(v.x, s1, sh1), 0.f);
            vals[1] = fmaxf(fmaf(v.y, s1, sh1), 0.f);
            vals[2] = fmaxf(fmaf(v.z, s1, sh1), 0.f);
            vals[3] = fmaxf(fmaf(v.w, s1, sh1), 0.f);
            int g = 4 * tid;
            int col = g / 5, p = g - 5 * col;
#pragma unroll
            for (int m = 0; m < 4; ++m) {
                int pm = p + m;
                int rr = (pm >= 5) ? pm - 5 : pm;
                int cc = col + ((pm >= 5) ? 1 : 0);
                a1s[cur][rr * 100 + cc] = vals[m];
            }
        }
        *(float4*)&w2s[cur][4 * tid] = pw0;
        if (tid < 8) *(float4*)&w2s[cur][4 * (tid + 192)] = pw1;
        if (ic + 1 < 32) fetch(ic + 1);       // global loads fly during compute
        __syncthreads();

#pragma unroll 2
        for (int p = 0; p < 5; ++p) {
            const float* xr = &a1s[cur][p * 100 + 4 * tg];
            float4 xa = *(const float4*)(xr);
            float4 xbv = *(const float4*)(xr + 4);
            float xv[8] = {xa.x, xa.y, xa.z, xa.w, xbv.x, xbv.y, xbv.z, xbv.w};
            const float* wr = &w2s[cur][p * 160 + oc0];
            float4 w0 = *(const float4*)(wr);
            float4 w1v = *(const float4*)(wr + 32);
            float4 w2v = *(const float4*)(wr + 64);
            float4 w3v = *(const float4*)(wr + 96);
            float4 w4v = *(const float4*)(wr + 128);
            float wj[5][4] = {{w0.x, w0.y, w0.z, w0.w},
                              {w1v.x, w1v.y, w1v.z, w1v.w},
                              {w2v.x, w2v.y, w2v.z, w2v.w},
                              {w3v.x, w3v.y, w3v.z, w3v.w},
                              {w4v.x, w4v.y, w4v.z, w4v.w}};
#pragma unroll
            for (int j = 0; j < 5; ++j)
#pragma unroll
                for (int jt = 0; jt < 4; ++jt) {
                    float xx = xv[jt + j];
#pragma unroll
                    for (int jo = 0; jo < 4; ++jo)
                        acc[jo][jt] = fmaf(wj[j][jo], xx, acc[jo][jt]);
                }
        }
    }

    float bias[4];
#pragma unroll
    for (int jo = 0; jo < 4; ++jo) bias[jo] = b2[oc0 + jo];

    float psum[4], psq[4];
#pragma unroll
    for (int jo = 0; jo < 4; ++jo) {
        float s = 0.f, q = 0.f;
#pragma unroll
        for (int jt = 0; jt < 4; ++jt) {
            int t2 = lt0 + jt;
            if (t2 < T2) {
                float v = acc[jo][jt] + bias[jo];
                y2[(size_t)(b * 32 + oc0 + jo) * T2 + t2] = v;
                s += v; q = fmaf(v, v, q);
            }
        }
        psum[jo] = s; psq[jo] = q;
    }
#pragma unroll
    for (int off = 32; off >= 8; off >>= 1) {
#pragma unroll
        for (int jo = 0; jo < 4; ++jo) {
            psum[jo] += __shfl_down(psum[jo], off, 64);
            psq[jo]  += __shfl_down(psq[jo],  off, 64);
        }
    }
    int lane = tid & 63, wvi = tid >> 6;   // 3 waves
    if (lane < 8) {
#pragma unroll
        for (int jo = 0; jo < 4; ++jo) {
            sred[((wvi * 8 + lane) * 4 + jo) * 2 + 0] = psum[jo];
            sred[((wvi * 8 + lane) * 4 + jo) * 2 + 1] = psq[jo];
        }
    }
    __syncthreads();
    if (tid < 64) {
        int oc = tid >> 1, which = tid & 1;
        int og = oc >> 2, jo = oc & 3;
        float v = 0.f;
#pragma unroll
        for (int w = 0; w < 3; ++w)
            v += sred[((w * 8 + og) * 4 + jo) * 2 + which];
        atomicAdd(&stats[64 + which * 32 + oc], v);
    }
}

// ---------------- projection + LayerNorm, writes xs[t][b][l] ----------------
// BN2 scale/shift computed in-block from raw stats.
__global__ __launch_bounds__(256, 2) void proj_kernel(const float* __restrict__ g2,
                                                      const float* __restrict__ be2,
                                                      const float* __restrict__ pw,
                                                      const float* __restrict__ pb,
                                                      const float* __restrict__ lng,
                                                      const float* __restrict__ lnb,
                                                      float* __restrict__ ws) {
    int b = blockIdx.x;
    int tid = threadIdx.x;
    __shared__ float a2s[3040];       // [f][t]
    __shared__ float pws[1056];       // [l][33]
    __shared__ float bns2[64];
    const float* stats = ws + OFS_STATS;
    const float* y2 = ws + OFS_Y2 + (size_t)b * (32 * T2);
    float* xsg = ws + OFS_XS;

    if (tid < 32) {
        float mean = stats[64 + tid] * (1.f / 48640.f);
        float var  = stats[96 + tid] * (1.f / 48640.f) - mean * mean;
        float s = g2[tid] * rsqrtf(var + 1e-5f);
        bns2[tid]      = s;
        bns2[32 + tid] = be2[tid] - mean * s;
    }
    __syncthreads();

    for (int f = 0; f < 32; ++f) {
        float s2  = bns2[f];
        float sh2 = bns2[32 + f];
        if (tid < T2)
            a2s[f * T2 + tid] = fmaxf(fmaf(y2[f * T2 + tid], s2, sh2), 0.f);
    }
    for (int i = tid; i < 1024; i += 256)
        pws[(i >> 5) * 33 + (i & 31)] = pw[i];

    int l = tid & 31, ts = tid >> 5;
    float pbv = pb[l], lg = lng[l], lb = lnb[l];
    __syncthreads();

    for (int it = 0; it < 12; ++it) {
        int t = ts + 8 * it;
        if (t < T2) {
            float v = pbv;
#pragma unroll
            for (int f = 0; f < 32; ++f)
                v = fmaf(a2s[f * T2 + t], pws[l * 33 + f], v);
            float sum = v;
#pragma unroll
            for (int off = 16; off >= 1; off >>= 1) sum += __shfl_xor(sum, off, 64);
            float mean = sum * (1.f / 32.f);
            float d = v - mean;
            float q = d * d;
#pragma unroll
            for (int off = 16; off >= 1; off >>= 1) q += __shfl_xor(q, off, 64);
            float o = d * rsqrtf(q * (1.f / 32.f) + 1e-5f) * lg + lb;
            xsg[(size_t)t * (NB * 32) + b * 32 + l] = o;
        }
    }
}

// ---------------- PLRNN scan + pooled mean + output projection ----------------
__global__ __launch_bounds__(64)
__attribute__((amdgpu_waves_per_eu(1, 1)))
void scan_kernel(const float* __restrict__ Am,
                 const float* __restrict__ Wm,
                 const float* __restrict__ hbp,
                 const float* __restrict__ ow,
                 const float* __restrict__ ob,
                 const float* __restrict__ ws,
                 float* __restrict__ out) {
    int b = blockIdx.x;
    int lane = threadIdx.x;
    int l = lane & 31, half = lane >> 5;
    __shared__ __align__(16) float hs[32];
    __shared__ __align__(16) float hds[64];
    __shared__ float ows[1056];

    float Wc[32], WT[32], Ah[16];
#pragma unroll
    for (int j = 0; j < 32; ++j) Wc[j] = Wm[j * HIDD + lane];          // W[j][lane]
#pragma unroll
    for (int m = 0; m < 32; ++m) WT[m] = Wm[l * HIDD + half * 32 + m]; // W[l][m-half]
#pragma unroll
    for (int j = 0; j < 16; ++j) Ah[j] = Am[l * 32 + half * 16 + j];   // A[l][j-half]
    float hbv = hbp[lane];
    for (int i = lane; i < 1024; i += 64)
        ows[(i >> 5) * 33 + (i & 31)] = ow[i];

    const float* xsg = ws + OFS_XS + b * 32;
    if (lane < 32) hs[l] = 0.f;
    float xv = xsg[l];
    float pool = 0.f;
    __syncthreads();

    for (int t = 0; t < T2; ++t) {
        __syncthreads();
        float4 hv[8];
#pragma unroll
        for (int q = 0; q < 8; ++q) hv[q] = *(const float4*)&hs[4 * q];
        float a0 = hbv, a1 = 0.f, a2 = 0.f, a3 = 0.f;
#pragma unroll
        for (int q = 0; q < 8; ++q) {
            a0 = fmaf(Wc[4 * q + 0], hv[q].x, a0);
            a1 = fmaf(Wc[4 * q + 1], hv[q].y, a1);
            a2 = fmaf(Wc[4 * q + 2], hv[q].z, a2);
            a3 = fmaf(Wc[4 * q + 3], hv[q].w, a3);
        }
        float hid = fmaxf((a0 + a1) + (a2 + a3), 0.f);
        float4 hl[4];
#pragma unroll
        for (int q = 0; q < 4; ++q) hl[q] = *(const float4*)&hs[half * 16 + 4 * q];
        float l0 = 0.f, l1 = 0.f;
#pragma unroll
        for (int q = 0; q < 4; ++q) {
            l0 = fmaf(Ah[4 * q + 0], hl[q].x, l0);
            l1 = fmaf(Ah[4 * q + 1], hl[q].y, l1);
            l0 = fmaf(Ah[4 * q + 2], hl[q].z, l0);
            l1 = fmaf(Ah[4 * q + 3], hl[q].w, l1);
        }
        float lin = l0 + l1;
        hds[lane] = hid;
        __syncthreads();
        float n0 = 0.f, n1 = 0.f, n2 = 0.f, n3 = 0.f;
#pragma unroll
        for (int q = 0; q < 8; ++q) {
            float4 d4 = *(const float4*)&hds[half * 32 + 4 * q];
            n0 = fmaf(WT[4 * q + 0], d4.x, n0);
            n1 = fmaf(WT[4 * q + 1], d4.y, n1);
            n2 = fmaf(WT[4 * q + 2], d4.z, n2);
            n3 = fmaf(WT[4 * q + 3], d4.w, n3);
        }
        float part = (n0 + n1) + (n2 + n3) + lin;
        part += __shfl_xor(part, 32, 64);
        float hnew = part + xv;
        pool += hnew;
        if (t + 1 < T2) xv = xsg[(size_t)(t + 1) * (NB * 32) + l];
        if (lane < 32) hs[l] = hnew;
    }

    __syncthreads();
    if (lane < 32) hs[l] = pool * (1.f / 95.f);
    __syncthreads();
    if (lane < 32) {
        float4 p0 = *(const float4*)&hs[0];
        float4 p1 = *(const float4*)&hs[4];
        float4 p2 = *(const float4*)&hs[8];
        float4 p3 = *(const float4*)&hs[12];
        float4 p4 = *(const float4*)&hs[16];
        float4 p5 = *(const float4*)&hs[20];
        float4 p6 = *(const float4*)&hs[24];
        float4 p7 = *(const float4*)&hs[28];
        float o = ob[l];
        const float* owr = &ows[l * 33];
        o = fmaf(owr[0],  p0.x, o); o = fmaf(owr[1],  p0.y, o);
        o = fmaf(owr[2],  p0.z, o); o = fmaf(owr[3],  p0.w, o);
        o = fmaf(owr[4],  p1.x, o); o = fmaf(owr[5],  p1.y, o);
        o = fmaf(owr[6],  p1.z, o); o = fmaf(owr[7],  p1.w, o);
        o = fmaf(owr[8],  p2.x, o); o = fmaf(owr[9],  p2.y, o);
        o = fmaf(owr[10], p2.z, o); o = fmaf(owr[11], p2.w, o);
        o = fmaf(owr[12], p3.x, o); o = fmaf(owr[13], p3.y, o);
        o = fmaf(owr[14], p3.z, o); o = fmaf(owr[15], p3.w, o);
        o = fmaf(owr[16], p4.x, o); o = fmaf(owr[17], p4.y, o);
        o = fmaf(owr[18], p4.z, o); o = fmaf(owr[19], p4.w, o);
        o = fmaf(owr[20], p5.x, o); o = fmaf(owr[21], p5.y, o);
        o = fmaf(owr[22], p5.z, o); o = fmaf(owr[23], p5.w, o);
        o = fmaf(owr[24], p6.x, o); o = fmaf(owr[25], p6.y, o);
        o = fmaf(owr[26], p6.z, o); o = fmaf(owr[27], p6.w, o);
        o = fmaf(owr[28], p7.x, o); o = fmaf(owr[29], p7.y, o);
        o = fmaf(owr[30], p7.z, o); o = fmaf(owr[31], p7.w, o);
        out[b * 32 + l] = o;
    }
}

extern "C" void kernel_launch(void* const* d_in, const int* in_sizes, int n_in,
                              void* d_out, int out_size, void* d_ws, size_t ws_size,
                              hipStream_t stream) {
    (void)in_sizes; (void)n_in; (void)out_size; (void)ws_size;
    const float* x   = (const float*)d_in[0];
    const float* w1  = (const float*)d_in[1];
    const float* b1  = (const float*)d_in[2];
    const float* g1  = (const float*)d_in[3];
    const float* be1 = (const float*)d_in[4];
    const float* w2  = (const float*)d_in[5];
    const float* b2  = (const float*)d_in[6];
    const float* g2  = (const float*)d_in[7];
    const float* be2 = (const float*)d_in[8];
    const float* pw  = (const float*)d_in[9];
    const float* pb  = (const float*)d_in[10];
    const float* lng = (const float*)d_in[11];
    const float* lnb = (const float*)d_in[12];
    const float* Am  = (const float*)d_in[13];
    const float* Wm  = (const float*)d_in[14];
    const float* hb  = (const float*)d_in[15];
    const float* ow  = (const float*)d_in[16];
    const float* ob  = (const float*)d_in[17];
    float* ws  = (float*)d_ws;
    float* out = (float*)d_out;

    prep_kernel<<<176, 256, 0, stream>>>(w1, w2, ws);
    conv1_kernel<<<1024, 256, 0, stream>>>(x, b1, ws);
    conv2_kernel<<<512, 192, 0, stream>>>(b2, g1, be1, ws);
    proj_kernel<<<512, 256, 0, stream>>>(g2, be2, pw, pb, lng, lnb, ws);
    scan_kernel<<<512, 64, 0, stream>>>(Am, Wm, hb, ow, ob, ws, out);
}